// Round 3
// baseline (292.263 us; speedup 1.0000x reference)
//
#include <hip/hip_runtime.h>
#include <hip/hip_bf16.h>

using bf16 = __hip_bfloat16;
typedef __attribute__((ext_vector_type(8))) short bf16x8;   // 8 bf16 = 4 VGPR
typedef __attribute__((ext_vector_type(4))) float f32x4;    // MFMA C/D frag

#define DEVI __device__ __forceinline__

constexpr int Bn = 2, Sn = 2048, Dn = 2048, Hn = 16, DHn = 128;
constexpr int Mn = Bn * Sn;   // 4096

DEVI void gload_lds16(const bf16* g, bf16* l) {
  __builtin_amdgcn_global_load_lds(
      (__attribute__((address_space(1))) void*)g,
      (__attribute__((address_space(3))) void*)l,
      16, 0, 0);
}

// ---------------- f32 -> bf16 convert (vectorized 8/thread) ----------------
__global__ __launch_bounds__(256) void cvt_bf16_k(const float* __restrict__ in,
                                                  bf16* __restrict__ out, int n8) {
  int i = blockIdx.x * 256 + threadIdx.x;
  if (i >= n8) return;
  const float4* p = (const float4*)in + (size_t)i * 2;
  float4 a = p[0], b = p[1];
  union { bf16 h[8]; bf16x8 v; } u;
  u.h[0] = __float2bfloat16(a.x); u.h[1] = __float2bfloat16(a.y);
  u.h[2] = __float2bfloat16(a.z); u.h[3] = __float2bfloat16(a.w);
  u.h[4] = __float2bfloat16(b.x); u.h[5] = __float2bfloat16(b.y);
  u.h[6] = __float2bfloat16(b.z); u.h[7] = __float2bfloat16(b.w);
  *((bf16x8*)out + i) = u.v;
}

// ---------------- 8-phase-family GEMM: C = A[M,K] * W[N,K]^T ---------------
// BM=256, BN=128, BK=64, 512 thr = 8 waves (4M x 2N), per-wave C 64x64.
// 2-slot LDS ring (96 KB), counted vmcnt(6), per-phase raw barriers + T2
// XOR-chunk swizzle (pre-swizzled global src, linear gload_lds dest), T5
// setprio around MFMA clusters. NTOT = total N-tiles (per-matrix 16 wide),
// NMAT selects which weight matrix / output slab a column tile belongs to.
template <int OUTF32, int NTOT, int NMAT>
__global__ __launch_bounds__(512, 2) void gemm8p(const bf16* __restrict__ A,
                                                 const bf16* __restrict__ W,
                                                 void* __restrict__ Cv) {
  constexpr int K = 2048;
  constexpr int NT = K / 64;                  // 32 K-tiles
  __shared__ bf16 smem[49152];                // 96 KB: 2 x (A 16384 + B 8192)

  const int nwg = NTOT * 16;
  const int orig = blockIdx.x;
  const int wgid = (orig & 7) * (nwg >> 3) + (orig >> 3);   // XCD swizzle (nwg%8==0)
  const int bm = wgid / NTOT;
  const int bnn = wgid % NTOT;
  constexpr int nper = NTOT / NMAT;
  const int z = bnn / nper;
  const int col0 = (bnn % nper) * 128;

  const int t = threadIdx.x;
  const int wave = t >> 6, lane = t & 63;
  const int wm = wave >> 1, wn = wave & 1;
  const int lr = lane & 15, lg = lane >> 4;
  const int trow = t >> 3, tch = t & 7;
  const int swz = lr & 7;

  const bf16* Ab = A + (size_t)(bm * 256 + trow) * K + ((tch ^ (trow & 7)) * 8);
  const bf16* Bb = W + (size_t)z * (2048 * 2048) +
                   (size_t)(col0 + trow) * K + ((tch ^ (trow & 7)) * 8);

  // stage unit u of K-tile kt into ring slot: u 0..3 = A quarters, 4..5 = B halves
  auto unit = [&](int slot, int kt, int u) {
    bf16* s = smem + slot * 24576;
    if (u < 4) {
      gload_lds16(Ab + (size_t)u * 64 * K + kt * 64, s + u * 4096 + t * 8);
    } else {
      int j = u - 4;
      gload_lds16(Bb + (size_t)j * 64 * K + kt * 64, s + 16384 + j * 4096 + t * 8);
    }
  };

  f32x4 acc[4][4];
  const f32x4 zf = {0.f, 0.f, 0.f, 0.f};
#pragma unroll
  for (int i = 0; i < 4; ++i)
#pragma unroll
    for (int j = 0; j < 4; ++j) acc[i][j] = zf;

  // prologue: tiles 0 and 1 in flight (6 loads each per wave)
#pragma unroll
  for (int u = 0; u < 6; ++u) unit(0, 0, u);
#pragma unroll
  for (int u = 0; u < 6; ++u) unit(1, 1, u);

  for (int kt = 0; kt < NT; ++kt) {
    if (kt == NT - 1) asm volatile("s_waitcnt vmcnt(0)" ::: "memory");
    else              asm volatile("s_waitcnt vmcnt(6)" ::: "memory");
    __builtin_amdgcn_s_barrier();             // tile kt staged for everyone

    const int slot = kt & 1;
    bf16* sA = smem + slot * 24576;
    bf16* sB = sA + 16384;

#pragma unroll
    for (int q = 0; q < 4; ++q) {
      const int mh = (q >> 1) * 2, nh = (q & 1) * 2;
      bf16x8 af[2][2], bv[2][2];
#pragma unroll
      for (int mi = 0; mi < 2; ++mi)
#pragma unroll
        for (int kk = 0; kk < 2; ++kk) {
          int row = wm * 64 + (mh + mi) * 16 + lr;
          af[mi][kk] = *(const bf16x8*)(sA + row * 64 + (((kk * 4 + lg) ^ swz) * 8));
        }
#pragma unroll
      for (int ni = 0; ni < 2; ++ni)
#pragma unroll
        for (int kk = 0; kk < 2; ++kk) {
          int row = wn * 64 + (nh + ni) * 16 + lr;
          bv[ni][kk] = *(const bf16x8*)(sB + row * 64 + (((kk * 4 + lg) ^ swz) * 8));
        }
      asm volatile("s_waitcnt lgkmcnt(0)" ::: "memory");
      __builtin_amdgcn_sched_barrier(0);      // rule 18: don't hoist MFMA above
      __builtin_amdgcn_s_barrier();           // all waves done reading this slot (q==3)
      __builtin_amdgcn_s_setprio(1);
      if (q < 3) {
#pragma unroll
        for (int kk = 0; kk < 2; ++kk)
#pragma unroll
          for (int mi = 0; mi < 2; ++mi)
#pragma unroll
            for (int ni = 0; ni < 2; ++ni)
              acc[mh + mi][nh + ni] = __builtin_amdgcn_mfma_f32_16x16x32_bf16(
                  af[mi][kk], bv[ni][kk], acc[mh + mi][nh + ni], 0, 0, 0);
      } else {
        const bool st = (kt + 2 < NT);
        if (st) { unit(slot, kt + 2, 0); unit(slot, kt + 2, 1); unit(slot, kt + 2, 2); }
#pragma unroll
        for (int mi = 0; mi < 2; ++mi)
#pragma unroll
          for (int ni = 0; ni < 2; ++ni)
            acc[mh + mi][nh + ni] = __builtin_amdgcn_mfma_f32_16x16x32_bf16(
                af[mi][0], bv[ni][0], acc[mh + mi][nh + ni], 0, 0, 0);
        if (st) { unit(slot, kt + 2, 3); unit(slot, kt + 2, 4); unit(slot, kt + 2, 5); }
#pragma unroll
        for (int mi = 0; mi < 2; ++mi)
#pragma unroll
          for (int ni = 0; ni < 2; ++ni)
            acc[mh + mi][nh + ni] = __builtin_amdgcn_mfma_f32_16x16x32_bf16(
                af[mi][1], bv[ni][1], acc[mh + mi][nh + ni], 0, 0, 0);
      }
      __builtin_amdgcn_s_setprio(0);
    }
  }

  // epilogue
  const int r0 = bm * 256 + wm * 64, c0 = col0 + wn * 64;
#pragma unroll
  for (int mm = 0; mm < 4; ++mm)
#pragma unroll
    for (int nn = 0; nn < 4; ++nn) {
      const int rr = r0 + mm * 16 + lg * 4;
      const int cc = c0 + nn * 16 + lr;
#pragma unroll
      for (int r = 0; r < 4; ++r) {
        float v = acc[mm][nn][r];
        if (OUTF32) {
          ((float*)Cv)[(size_t)(rr + r) * 2048 + cc] = v;
        } else {
          bf16* C = (bf16*)Cv + (size_t)z * (Mn * 2048);
          C[(size_t)(rr + r) * 2048 + cc] = __float2bfloat16(v);
        }
      }
    }
}

// ---------------- V transpose: per (b,h)  V[2048,128] -> VT[128,2048] ------
__global__ __launch_bounds__(256, 2) void transpose_v(const bf16* __restrict__ V,
                                                      bf16* __restrict__ VT) {
  __shared__ bf16 tile[128 * 128];   // 32 KB, chunk-XOR-swizzled
  const int kt = blockIdx.x, bh = blockIdx.y;
  const bf16* Vh = V + (size_t)bh * (Sn * DHn);
  bf16* VTh = VT + (size_t)bh * (DHn * Sn);
  const int t = threadIdx.x;
  const int rr = t >> 4, cc = t & 15;
#pragma unroll
  for (int i = 0; i < 8; ++i) {
    int r = rr + i * 16;
    int ch = cc ^ ((r >> 3) & 7);
    *(bf16x8*)(tile + r * 128 + ch * 8) =
        *(const bf16x8*)(Vh + (size_t)(kt * 128 + r) * DHn + cc * 8);
  }
  __syncthreads();
  const int dr = t >> 4, li = t & 15;
#pragma unroll
  for (int i = 0; i < 8; ++i) {
    int dh = dr + i * 16;
    union { bf16 h[8]; bf16x8 v; } u;
#pragma unroll
    for (int j = 0; j < 8; ++j) {
      int k = li * 8 + j;
      int ch = (dh >> 3) ^ ((k >> 3) & 7);
      u.h[j] = tile[k * 128 + ch * 8 + (dh & 7)];
    }
    *(bf16x8*)(VTh + (size_t)dh * Sn + kt * 128 + li * 8) = u.v;
  }
}

// ---------------- causal flash attention v2 --------------------------------
// QBLK=64, 4 waves x 16 q-rows. Block pairs qb=j with qb=31-j (33 tiles each,
// perfectly balanced). 2-phase double-buffered K/VT staging via
// global_load_lds with XOR chunk swizzle.
__global__ __launch_bounds__(256, 2) void attn_k2(const bf16* __restrict__ Q,
                                                  const bf16* __restrict__ K,
                                                  const bf16* __restrict__ VT,
                                                  bf16* __restrict__ Mg) {
  __shared__ bf16 smem[36864];         // 72 KB
  bf16* sK0 = smem;                    // [64][128] swizzled
  bf16* sK1 = smem + 8192;
  bf16* sV0 = smem + 16384;            // [128][64] swizzled
  bf16* sV1 = smem + 24576;
  bf16* sP  = smem + 32768;            // 4 waves x [16][64] swizzled
  bf16* sO  = smem;                    // epilogue reuse [64][128] swizzled

  const int j = blockIdx.x;            // pair index 0..15
  const int bh = blockIdx.y;
  const bf16* Qh = Q + (size_t)bh * (Sn * DHn);
  const bf16* Kh = K + (size_t)bh * (Sn * DHn);
  const bf16* VTh = VT + (size_t)bh * (DHn * Sn);
  const int b = bh >> 4, h = bh & 15;

  const int t = threadIdx.x, wave = t >> 6, lane = t & 63;
  const int lr = lane & 15, lg = lane >> 4;

  auto STAGE = [&](int buf, int kt) {
    bf16* dK = buf ? sK1 : sK0;
    bf16* dV = buf ? sV1 : sV0;
#pragma unroll
    for (int i = 0; i < 4; ++i) {
      int c = i * 256 + t;
      int row = c >> 4, c16 = c & 15;
      gload_lds16(Kh + (size_t)(kt * 64 + row) * DHn + ((c16 ^ (row & 7)) * 8),
                  dK + c * 8);
    }
#pragma unroll
    for (int i = 0; i < 4; ++i) {
      int c = i * 256 + t;
      int row = c >> 3, c8 = c & 7;
      gload_lds16(VTh + (size_t)row * Sn + kt * 64 + ((c8 ^ (row & 7)) * 8),
                  dV + c * 8);
    }
  };

  const f32x4 zf = {0.f, 0.f, 0.f, 0.f};

  for (int pi = 0; pi < 2; ++pi) {
    const int qb = pi ? (31 - j) : j;
    const int nt = qb + 1;
    const int q0 = qb * 64 + wave * 16;

    bf16x8 qf[4];
#pragma unroll
    for (int kk = 0; kk < 4; ++kk)
      qf[kk] = *(const bf16x8*)(Qh + (size_t)(q0 + lr) * DHn + kk * 32 + lg * 8);

    f32x4 o[8];
#pragma unroll
    for (int d = 0; d < 8; ++d) o[d] = zf;
    float mrun[4], lrun[4];
#pragma unroll
    for (int r = 0; r < 4; ++r) { mrun[r] = -3e38f; lrun[r] = 0.f; }

    STAGE(0, 0);
    __syncthreads();   // drains vmcnt(0): buf0 ready
    int cur = 0;

    for (int kt = 0; kt < nt; ++kt) {
      if (kt + 1 < nt) STAGE(cur ^ 1, kt + 1);   // prefetch in flight over compute

      bf16* sKc = cur ? sK1 : sK0;
      bf16* sVc = cur ? sV1 : sV0;

      // S = Q K^T
      f32x4 sfr[4];
#pragma unroll
      for (int nn = 0; nn < 4; ++nn) sfr[nn] = zf;
#pragma unroll
      for (int kk = 0; kk < 4; ++kk)
#pragma unroll
        for (int nn = 0; nn < 4; ++nn) {
          int row = nn * 16 + lr;
          int ch = (kk * 4 + lg) ^ (row & 7);
          bf16x8 kf = *(const bf16x8*)(sKc + row * DHn + ch * 8);
          sfr[nn] = __builtin_amdgcn_mfma_f32_16x16x32_bf16(qf[kk], kf, sfr[nn], 0, 0, 0);
        }

      // online softmax (rows: lg*4+r, cols: nn*16+lr)
      const bool maskt = (kt == nt - 1);
      float pv[4][4];
#pragma unroll
      for (int nn = 0; nn < 4; ++nn)
#pragma unroll
        for (int r = 0; r < 4; ++r) {
          float v = sfr[nn][r] * (1.0f / 128.0f);
          if (maskt) {
            int kg = kt * 64 + nn * 16 + lr;
            int qg = q0 + lg * 4 + r;
            if (kg > qg) v = -1e30f;
          }
          pv[nn][r] = v;
        }
      float mnew[4], alpha[4], rsum[4];
#pragma unroll
      for (int r = 0; r < 4; ++r) {
        float rm = fmaxf(fmaxf(pv[0][r], pv[1][r]), fmaxf(pv[2][r], pv[3][r]));
        rm = fmaxf(rm, __shfl_xor(rm, 1));
        rm = fmaxf(rm, __shfl_xor(rm, 2));
        rm = fmaxf(rm, __shfl_xor(rm, 4));
        rm = fmaxf(rm, __shfl_xor(rm, 8));
        mnew[r] = fmaxf(mrun[r], rm);
        alpha[r] = __expf(mrun[r] - mnew[r]);
        mrun[r] = mnew[r];
        rsum[r] = 0.f;
      }
#pragma unroll
      for (int nn = 0; nn < 4; ++nn)
#pragma unroll
        for (int r = 0; r < 4; ++r) {
          float p = __expf(pv[nn][r] - mnew[r]);
          pv[nn][r] = p;
          rsum[r] += p;
        }
#pragma unroll
      for (int r = 0; r < 4; ++r) {
        float s = rsum[r];
        s += __shfl_xor(s, 1); s += __shfl_xor(s, 2);
        s += __shfl_xor(s, 4); s += __shfl_xor(s, 8);
        lrun[r] = lrun[r] * alpha[r] + s;
      }
#pragma unroll
      for (int d = 0; d < 8; ++d)
#pragma unroll
        for (int r = 0; r < 4; ++r) o[d][r] *= alpha[r];

      // P -> LDS (swizzled), per-wave region
#pragma unroll
      for (int nn = 0; nn < 4; ++nn)
#pragma unroll
        for (int r = 0; r < 4; ++r) {
          int row = lg * 4 + r;
          int chk = (nn * 2 + (lr >> 3)) ^ (row & 7);
          sP[wave * 1024 + row * 64 + chk * 8 + (lr & 7)] = __float2bfloat16(pv[nn][r]);
        }

      // O += P V
      bf16x8 pf[2];
#pragma unroll
      for (int kk = 0; kk < 2; ++kk) {
        int ch = (kk * 4 + lg) ^ (lr & 7);
        pf[kk] = *(const bf16x8*)(sP + wave * 1024 + lr * 64 + ch * 8);
      }
#pragma unroll
      for (int d = 0; d < 8; ++d)
#pragma unroll
        for (int kk = 0; kk < 2; ++kk) {
          int vrow = d * 16 + lr;
          int vch = (kk * 4 + lg) ^ (vrow & 7);
          bf16x8 vf = *(const bf16x8*)(sVc + vrow * 64 + vch * 8);
          o[d] = __builtin_amdgcn_mfma_f32_16x16x32_bf16(pf[kk], vf, o[d], 0, 0, 0);
        }

      __syncthreads();   // drains prefetch vmcnt + all ds reads of cur
      cur ^= 1;
    }

    // epilogue: normalize, stage to LDS (swizzled), coalesced global write
    float inv[4];
#pragma unroll
    for (int r = 0; r < 4; ++r) inv[r] = 1.0f / lrun[r];
#pragma unroll
    for (int d = 0; d < 8; ++d)
#pragma unroll
      for (int r = 0; r < 4; ++r) {
        int row = wave * 16 + lg * 4 + r;
        int col = d * 16 + lr;
        int chk = ((col >> 3) ^ (row & 7));
        sO[row * 128 + chk * 8 + (col & 7)] = __float2bfloat16(o[d][r] * inv[r]);
      }
    __syncthreads();
    bf16* Mh = Mg + ((size_t)(b * Sn + qb * 64)) * Dn + h * DHn;
#pragma unroll
    for (int i = 0; i < 4; ++i) {
      int row = (t >> 4) + i * 16;
      int c16 = t & 15;
      *(bf16x8*)(Mh + (size_t)row * Dn + c16 * 8) =
          *(const bf16x8*)(sO + row * 128 + ((c16 ^ (row & 7)) * 8));
    }
    __syncthreads();   // sO region is re-staged by next pass
  }
}

// ---------------------------------------------------------------------------
extern "C" void kernel_launch(void* const* d_in, const int* in_sizes, int n_in,
                              void* d_out, int out_size, void* d_ws, size_t ws_size,
                              hipStream_t stream) {
  const float* x = (const float*)d_in[0];
  const float* Wq = (const float*)d_in[1];
  const float* Wk = (const float*)d_in[2];
  const float* Wv = (const float*)d_in[3];
  const float* Wo = (const float*)d_in[4];
  float* out = (float*)d_out;

  char* ws = (char*)d_ws;
  bf16* xb = (bf16*)ws;            ws += (size_t)Mn * Dn * 2;        // 16 MB
  bf16* Wb = (bf16*)ws;            ws += (size_t)4 * Dn * Dn * 2;    // 32 MB (q,k,v,o)
  bf16* QKV = (bf16*)ws;           ws += (size_t)3 * Mn * Dn * 2;    // 48 MB
  bf16* VT = (bf16*)ws;            ws += (size_t)Bn * Hn * DHn * Sn * 2; // 16 MB
  bf16* Mg = (bf16*)ws;            ws += (size_t)Mn * Dn * 2;        // 16 MB

  const int nx8 = Mn * Dn / 8;     // 1048576
  const int nw8 = Dn * Dn / 8;     // 524288
  cvt_bf16_k<<<nx8 / 256, 256, 0, stream>>>(x, xb, nx8);
  cvt_bf16_k<<<nw8 / 256, 256, 0, stream>>>(Wq, Wb + 0 * (size_t)Dn * Dn, nw8);
  cvt_bf16_k<<<nw8 / 256, 256, 0, stream>>>(Wk, Wb + 1 * (size_t)Dn * Dn, nw8);
  cvt_bf16_k<<<nw8 / 256, 256, 0, stream>>>(Wv, Wb + 2 * (size_t)Dn * Dn, nw8);
  cvt_bf16_k<<<nw8 / 256, 256, 0, stream>>>(Wo, Wb + 3 * (size_t)Dn * Dn, nw8);

  // Q,K,V = x @ W{q,k,v}^T  -> bf16 (fused over N = 3*2048; 768 blocks = 3/CU)
  gemm8p<0, 48, 3><<<768, 512, 0, stream>>>(xb, Wb, (void*)QKV);

  // per-head V transpose
  transpose_v<<<dim3(16, 32), 256, 0, stream>>>(QKV + 2 * (size_t)Mn * Dn, VT);

  // causal attention -> merged [4096, 2048] bf16
  attn_k2<<<dim3(16, 32), 256, 0, stream>>>(QKV, QKV + (size_t)Mn * Dn, VT, Mg);

  // out = merged @ Wo^T -> f32 (256 blocks = 1/CU)
  gemm8p<1, 16, 1><<<256, 512, 0, stream>>>(Mg, Wb + 3 * (size_t)Dn * Dn, (void*)out);
}

// Round 5
// 266.553 us; speedup vs baseline: 1.0965x; 1.0965x over previous
//
#include <hip/hip_runtime.h>
#include <hip/hip_bf16.h>

using bf16 = __hip_bfloat16;
typedef __attribute__((ext_vector_type(8))) short bf16x8;   // 8 bf16 = 4 VGPR
typedef __attribute__((ext_vector_type(4))) float f32x4;    // MFMA C/D frag

#define DEVI __device__ __forceinline__

constexpr int Bn = 2, Sn = 2048, Dn = 2048, Hn = 16, DHn = 128;
constexpr int Mn = Bn * Sn;   // 4096

DEVI void gload_lds16(const bf16* g, bf16* l) {
  __builtin_amdgcn_global_load_lds(
      (__attribute__((address_space(1))) void*)g,
      (__attribute__((address_space(3))) void*)l,
      16, 0, 0);
}

// ---------------- f32 -> bf16 convert (vectorized 8/thread) ----------------
__global__ __launch_bounds__(256) void cvt_bf16_k(const float* __restrict__ in,
                                                  bf16* __restrict__ out, int n8) {
  int i = blockIdx.x * 256 + threadIdx.x;
  if (i >= n8) return;
  const float4* p = (const float4*)in + (size_t)i * 2;
  float4 a = p[0], b = p[1];
  union { bf16 h[8]; bf16x8 v; } u;
  u.h[0] = __float2bfloat16(a.x); u.h[1] = __float2bfloat16(a.y);
  u.h[2] = __float2bfloat16(a.z); u.h[3] = __float2bfloat16(a.w);
  u.h[4] = __float2bfloat16(b.x); u.h[5] = __float2bfloat16(b.y);
  u.h[6] = __float2bfloat16(b.z); u.h[7] = __float2bfloat16(b.w);
  *((bf16x8*)out + i) = u.v;
}

// ---------------- GEMM Y: C = A[M,K] * W[N,K]^T ----------------------------
// BM=256, BN=128, BK=32, 256 thr = 4 waves (2M x 2N), per-wave C = 128x64
// (acc[8][4], 16 MFMA per phase, 2 phases per K-tile). 2-slot LDS ring
// (48 KB -> 2 blocks/CU), counted vmcnt, phase-spread staging, T2 swizzle,
// T5 setprio.
// Staging ledger (per wave, 6 loads/tile):
//   tile kt's A0,A2,B0,B1 issued at kt-2 phase1; A1,A3 at kt-1 phase0.
//   FIFO at tile-kt top: [kt A0A2B0B1][kt A1A3][kt+1 A0A2B0B1]
//   -> vmcnt(4) retires all of tile kt; LAST tile must use vmcnt(0).
// Tile top = {vmcnt; barrier} BEFORE any ds_read of the tile (round-4 bug fix).
template <int OUTF32, int NTOT, int NMAT>
__global__ __launch_bounds__(256, 2) void gemmY(const bf16* __restrict__ A,
                                                const bf16* __restrict__ W,
                                                void* __restrict__ Cv) {
  constexpr int K = 2048, BK = 32, NT = K / BK;   // 64 K-tiles
  __shared__ bf16 smem[2 * 12288];   // 48 KB: per slot A[256][32] + B[128][32]

  const int nwg = NTOT * 16;
  const int orig = blockIdx.x;
  const int wgid = (orig & 7) * (nwg >> 3) + (orig >> 3);   // XCD swizzle (nwg%8==0)
  const int bm = wgid / NTOT;
  const int bnn = wgid % NTOT;
  constexpr int nper = NTOT / NMAT;
  const int z = bnn / nper;
  const int col0 = (bnn % nper) * 128;

  const int t = threadIdx.x;
  const int wave = t >> 6, lane = t & 63;
  const int wm = wave >> 1, wn = wave & 1;
  const int lr = lane & 15, lg = lane >> 4;
  const int rch = ((lg ^ ((lr >> 1) & 3)) * 8);       // swizzled read chunk
  const int srow = t >> 2;                            // staging row in unit
  const int sch = (t & 3) ^ ((t >> 3) & 3);           // pre-swizzled src chunk

  const bf16* Ab = A + (size_t)(bm * 256 + srow) * K + sch * 8;
  const bf16* Bb = W + (size_t)z * (2048 * 2048) +
                   (size_t)(col0 + srow) * K + sch * 8;

  auto stgA = [&](int slot, int kt, int u) {
    gload_lds16(Ab + (size_t)u * 64 * K + kt * 32,
                smem + slot * 12288 + u * 2048 + t * 8);
  };
  auto stgB = [&](int slot, int kt, int v) {
    gload_lds16(Bb + (size_t)v * 64 * K + kt * 32,
                smem + slot * 12288 + 8192 + v * 2048 + t * 8);
  };

  f32x4 acc[8][4];
  const f32x4 zf = {0.f, 0.f, 0.f, 0.f};
#pragma unroll
  for (int i = 0; i < 8; ++i)
#pragma unroll
    for (int j = 0; j < 4; ++j) acc[i][j] = zf;

  // prologue: tile0 complete (6 units), tile1 partial (A0,A2,B0,B1)
  stgA(0, 0, 0); stgA(0, 0, 1); stgA(0, 0, 2); stgA(0, 0, 3);
  stgB(0, 0, 0); stgB(0, 0, 1);
  stgA(1, 1, 0); stgA(1, 1, 2); stgB(1, 1, 0); stgB(1, 1, 1);

#pragma unroll 2
  for (int kt = 0; kt < NT; ++kt) {
    const int slot = kt & 1;
    const bf16* sAb = smem + slot * 12288;
    const bf16* sBb = sAb + 8192;

    // ---- tile top: guarantee slot kt fully landed, publish to all waves ----
    if (kt == NT - 1) asm volatile("s_waitcnt vmcnt(0)" ::: "memory");
    else              asm volatile("s_waitcnt vmcnt(4)" ::: "memory");
    __builtin_amdgcn_s_barrier();

    // ---- phase 0: af(mh=0) + bv(all); stage kt+1's A1,A3 ----
    bf16x8 af[4], bv[4];
#pragma unroll
    for (int i = 0; i < 4; ++i)
      af[i] = *(const bf16x8*)(sAb + (wm * 128 + i * 16 + lr) * 32 + rch);
#pragma unroll
    for (int n = 0; n < 4; ++n)
      bv[n] = *(const bf16x8*)(sBb + (wn * 64 + n * 16 + lr) * 32 + rch);
    if (kt + 1 < NT) { stgA(slot ^ 1, kt + 1, 1); stgA(slot ^ 1, kt + 1, 3); }
    asm volatile("s_waitcnt lgkmcnt(0)" ::: "memory");
    __builtin_amdgcn_sched_barrier(0);      // rule 18
    __builtin_amdgcn_s_setprio(1);
#pragma unroll
    for (int i = 0; i < 4; ++i)
#pragma unroll
      for (int n = 0; n < 4; ++n)
        acc[i][n] = __builtin_amdgcn_mfma_f32_16x16x32_bf16(af[i], bv[n], acc[i][n], 0, 0, 0);
    __builtin_amdgcn_s_setprio(0);
    __builtin_amdgcn_s_barrier();           // A0,A2,B0,B1 of slot kt now dead

    // ---- phase 1: af(mh=1); stage kt+2's A0,A2,B0,B1 into freed regions ----
#pragma unroll
    for (int i = 0; i < 4; ++i)
      af[i] = *(const bf16x8*)(sAb + (wm * 128 + 64 + i * 16 + lr) * 32 + rch);
    if (kt + 2 < NT) {
      stgA(slot, kt + 2, 0); stgA(slot, kt + 2, 2);
      stgB(slot, kt + 2, 0); stgB(slot, kt + 2, 1);
    }
    asm volatile("s_waitcnt lgkmcnt(0)" ::: "memory");
    __builtin_amdgcn_sched_barrier(0);
    __builtin_amdgcn_s_setprio(1);
#pragma unroll
    for (int i = 0; i < 4; ++i)
#pragma unroll
      for (int n = 0; n < 4; ++n)
        acc[4 + i][n] = __builtin_amdgcn_mfma_f32_16x16x32_bf16(af[i], bv[n], acc[4 + i][n], 0, 0, 0);
    __builtin_amdgcn_s_setprio(0);
    // next tile-top barrier closes this phase (all waves' reads drained
    // before their MFMA via lgkmcnt(0), so stores into A1/A3 issued after
    // the next top barrier are safe).
  }

  // epilogue
  const int r0 = bm * 256 + wm * 128, c0 = col0 + wn * 64;
#pragma unroll
  for (int mm = 0; mm < 8; ++mm)
#pragma unroll
    for (int nn = 0; nn < 4; ++nn) {
      const int rr = r0 + mm * 16 + lg * 4;
      const int cc = c0 + nn * 16 + lr;
#pragma unroll
      for (int r = 0; r < 4; ++r) {
        float v = acc[mm][nn][r];
        if (OUTF32) {
          ((float*)Cv)[(size_t)(rr + r) * 2048 + cc] = v;
        } else {
          bf16* C = (bf16*)Cv + (size_t)z * (Mn * 2048);
          C[(size_t)(rr + r) * 2048 + cc] = __float2bfloat16(v);
        }
      }
    }
}

// ---------------- V transpose: per (b,h)  V[2048,128] -> VT[128,2048] ------
__global__ __launch_bounds__(256, 2) void transpose_v(const bf16* __restrict__ V,
                                                      bf16* __restrict__ VT) {
  __shared__ bf16 tile[128 * 128];   // 32 KB, chunk-XOR-swizzled
  const int kt = blockIdx.x, bh = blockIdx.y;
  const bf16* Vh = V + (size_t)bh * (Sn * DHn);
  bf16* VTh = VT + (size_t)bh * (DHn * Sn);
  const int t = threadIdx.x;
  const int rr = t >> 4, cc = t & 15;
#pragma unroll
  for (int i = 0; i < 8; ++i) {
    int r = rr + i * 16;
    int ch = cc ^ ((r >> 3) & 7);
    *(bf16x8*)(tile + r * 128 + ch * 8) =
        *(const bf16x8*)(Vh + (size_t)(kt * 128 + r) * DHn + cc * 8);
  }
  __syncthreads();
  const int dr = t >> 4, li = t & 15;
#pragma unroll
  for (int i = 0; i < 8; ++i) {
    int dh = dr + i * 16;
    union { bf16 h[8]; bf16x8 v; } u;
#pragma unroll
    for (int j = 0; j < 8; ++j) {
      int k = li * 8 + j;
      int ch = (dh >> 3) ^ ((k >> 3) & 7);
      u.h[j] = tile[k * 128 + ch * 8 + (dh & 7)];
    }
    *(bf16x8*)(VTh + (size_t)dh * Sn + kt * 128 + li * 8) = u.v;
  }
}

// ---------------- causal flash attention v2 --------------------------------
// QBLK=64, 4 waves x 16 q-rows. Block pairs qb=j with qb=31-j (33 tiles each,
// perfectly balanced). 2-phase double-buffered K/VT staging via
// global_load_lds with XOR chunk swizzle.
__global__ __launch_bounds__(256, 2) void attn_k2(const bf16* __restrict__ Q,
                                                  const bf16* __restrict__ K,
                                                  const bf16* __restrict__ VT,
                                                  bf16* __restrict__ Mg) {
  __shared__ bf16 smem[36864];         // 72 KB
  bf16* sK0 = smem;                    // [64][128] swizzled
  bf16* sK1 = smem + 8192;
  bf16* sV0 = smem + 16384;            // [128][64] swizzled
  bf16* sV1 = smem + 24576;
  bf16* sP  = smem + 32768;            // 4 waves x [16][64] swizzled
  bf16* sO  = smem;                    // epilogue reuse [64][128] swizzled

  const int j = blockIdx.x;            // pair index 0..15
  const int bh = blockIdx.y;
  const bf16* Qh = Q + (size_t)bh * (Sn * DHn);
  const bf16* Kh = K + (size_t)bh * (Sn * DHn);
  const bf16* VTh = VT + (size_t)bh * (DHn * Sn);
  const int b = bh >> 4, h = bh & 15;

  const int t = threadIdx.x, wave = t >> 6, lane = t & 63;
  const int lr = lane & 15, lg = lane >> 4;

  auto STAGE = [&](int buf, int kt) {
    bf16* dK = buf ? sK1 : sK0;
    bf16* dV = buf ? sV1 : sV0;
#pragma unroll
    for (int i = 0; i < 4; ++i) {
      int c = i * 256 + t;
      int row = c >> 4, c16 = c & 15;
      gload_lds16(Kh + (size_t)(kt * 64 + row) * DHn + ((c16 ^ (row & 7)) * 8),
                  dK + c * 8);
    }
#pragma unroll
    for (int i = 0; i < 4; ++i) {
      int c = i * 256 + t;
      int row = c >> 3, c8 = c & 7;
      gload_lds16(VTh + (size_t)row * Sn + kt * 64 + ((c8 ^ (row & 7)) * 8),
                  dV + c * 8);
    }
  };

  const f32x4 zf = {0.f, 0.f, 0.f, 0.f};

  for (int pi = 0; pi < 2; ++pi) {
    const int qb = pi ? (31 - j) : j;
    const int nt = qb + 1;
    const int q0 = qb * 64 + wave * 16;

    bf16x8 qf[4];
#pragma unroll
    for (int kk = 0; kk < 4; ++kk)
      qf[kk] = *(const bf16x8*)(Qh + (size_t)(q0 + lr) * DHn + kk * 32 + lg * 8);

    f32x4 o[8];
#pragma unroll
    for (int d = 0; d < 8; ++d) o[d] = zf;
    float mrun[4], lrun[4];
#pragma unroll
    for (int r = 0; r < 4; ++r) { mrun[r] = -3e38f; lrun[r] = 0.f; }

    STAGE(0, 0);
    __syncthreads();   // drains vmcnt(0): buf0 ready
    int cur = 0;

    for (int kt = 0; kt < nt; ++kt) {
      if (kt + 1 < nt) STAGE(cur ^ 1, kt + 1);   // prefetch in flight over compute

      bf16* sKc = cur ? sK1 : sK0;
      bf16* sVc = cur ? sV1 : sV0;

      // S = Q K^T
      f32x4 sfr[4];
#pragma unroll
      for (int nn = 0; nn < 4; ++nn) sfr[nn] = zf;
#pragma unroll
      for (int kk = 0; kk < 4; ++kk)
#pragma unroll
        for (int nn = 0; nn < 4; ++nn) {
          int row = nn * 16 + lr;
          int ch = (kk * 4 + lg) ^ (row & 7);
          bf16x8 kf = *(const bf16x8*)(sKc + row * DHn + ch * 8);
          sfr[nn] = __builtin_amdgcn_mfma_f32_16x16x32_bf16(qf[kk], kf, sfr[nn], 0, 0, 0);
        }

      // online softmax (rows: lg*4+r, cols: nn*16+lr)
      const bool maskt = (kt == nt - 1);
      float pv[4][4];
#pragma unroll
      for (int nn = 0; nn < 4; ++nn)
#pragma unroll
        for (int r = 0; r < 4; ++r) {
          float v = sfr[nn][r] * (1.0f / 128.0f);
          if (maskt) {
            int kg = kt * 64 + nn * 16 + lr;
            int qg = q0 + lg * 4 + r;
            if (kg > qg) v = -1e30f;
          }
          pv[nn][r] = v;
        }
      float mnew[4], alpha[4], rsum[4];
#pragma unroll
      for (int r = 0; r < 4; ++r) {
        float rm = fmaxf(fmaxf(pv[0][r], pv[1][r]), fmaxf(pv[2][r], pv[3][r]));
        rm = fmaxf(rm, __shfl_xor(rm, 1));
        rm = fmaxf(rm, __shfl_xor(rm, 2));
        rm = fmaxf(rm, __shfl_xor(rm, 4));
        rm = fmaxf(rm, __shfl_xor(rm, 8));
        mnew[r] = fmaxf(mrun[r], rm);
        alpha[r] = __expf(mrun[r] - mnew[r]);
        mrun[r] = mnew[r];
        rsum[r] = 0.f;
      }
#pragma unroll
      for (int nn = 0; nn < 4; ++nn)
#pragma unroll
        for (int r = 0; r < 4; ++r) {
          float p = __expf(pv[nn][r] - mnew[r]);
          pv[nn][r] = p;
          rsum[r] += p;
        }
#pragma unroll
      for (int r = 0; r < 4; ++r) {
        float s = rsum[r];
        s += __shfl_xor(s, 1); s += __shfl_xor(s, 2);
        s += __shfl_xor(s, 4); s += __shfl_xor(s, 8);
        lrun[r] = lrun[r] * alpha[r] + s;
      }
#pragma unroll
      for (int d = 0; d < 8; ++d)
#pragma unroll
        for (int r = 0; r < 4; ++r) o[d][r] *= alpha[r];

      // P -> LDS (swizzled), per-wave region
#pragma unroll
      for (int nn = 0; nn < 4; ++nn)
#pragma unroll
        for (int r = 0; r < 4; ++r) {
          int row = lg * 4 + r;
          int chk = (nn * 2 + (lr >> 3)) ^ (row & 7);
          sP[wave * 1024 + row * 64 + chk * 8 + (lr & 7)] = __float2bfloat16(pv[nn][r]);
        }

      // O += P V
      bf16x8 pf[2];
#pragma unroll
      for (int kk = 0; kk < 2; ++kk) {
        int ch = (kk * 4 + lg) ^ (lr & 7);
        pf[kk] = *(const bf16x8*)(sP + wave * 1024 + lr * 64 + ch * 8);
      }
#pragma unroll
      for (int d = 0; d < 8; ++d)
#pragma unroll
        for (int kk = 0; kk < 2; ++kk) {
          int vrow = d * 16 + lr;
          int vch = (kk * 4 + lg) ^ (vrow & 7);
          bf16x8 vf = *(const bf16x8*)(sVc + vrow * 64 + vch * 8);
          o[d] = __builtin_amdgcn_mfma_f32_16x16x32_bf16(pf[kk], vf, o[d], 0, 0, 0);
        }

      __syncthreads();   // drains prefetch vmcnt + all ds reads of cur
      cur ^= 1;
    }

    // epilogue: normalize, stage to LDS (swizzled), coalesced global write
    float inv[4];
#pragma unroll
    for (int r = 0; r < 4; ++r) inv[r] = 1.0f / lrun[r];
#pragma unroll
    for (int d = 0; d < 8; ++d)
#pragma unroll
      for (int r = 0; r < 4; ++r) {
        int row = wave * 16 + lg * 4 + r;
        int col = d * 16 + lr;
        int chk = ((col >> 3) ^ (row & 7));
        sO[row * 128 + chk * 8 + (col & 7)] = __float2bfloat16(o[d][r] * inv[r]);
      }
    __syncthreads();
    bf16* Mh = Mg + ((size_t)(b * Sn + qb * 64)) * Dn + h * DHn;
#pragma unroll
    for (int i = 0; i < 4; ++i) {
      int row = (t >> 4) + i * 16;
      int c16 = t & 15;
      *(bf16x8*)(Mh + (size_t)row * Dn + c16 * 8) =
          *(const bf16x8*)(sO + row * 128 + ((c16 ^ (row & 7)) * 8));
    }
    __syncthreads();   // sO region is re-staged by next pass
  }
}

// ---------------------------------------------------------------------------
extern "C" void kernel_launch(void* const* d_in, const int* in_sizes, int n_in,
                              void* d_out, int out_size, void* d_ws, size_t ws_size,
                              hipStream_t stream) {
  const float* x = (const float*)d_in[0];
  const float* Wq = (const float*)d_in[1];
  const float* Wk = (const float*)d_in[2];
  const float* Wv = (const float*)d_in[3];
  const float* Wo = (const float*)d_in[4];
  float* out = (float*)d_out;

  char* ws = (char*)d_ws;
  bf16* xb = (bf16*)ws;            ws += (size_t)Mn * Dn * 2;        // 16 MB
  bf16* Wb = (bf16*)ws;            ws += (size_t)4 * Dn * Dn * 2;    // 32 MB (q,k,v,o)
  bf16* QKV = (bf16*)ws;           ws += (size_t)3 * Mn * Dn * 2;    // 48 MB
  bf16* VT = (bf16*)ws;            ws += (size_t)Bn * Hn * DHn * Sn * 2; // 16 MB
  bf16* Mg = (bf16*)ws;            ws += (size_t)Mn * Dn * 2;        // 16 MB

  const int nx8 = Mn * Dn / 8;     // 1048576
  const int nw8 = Dn * Dn / 8;     // 524288
  cvt_bf16_k<<<nx8 / 256, 256, 0, stream>>>(x, xb, nx8);
  cvt_bf16_k<<<nw8 / 256, 256, 0, stream>>>(Wq, Wb + 0 * (size_t)Dn * Dn, nw8);
  cvt_bf16_k<<<nw8 / 256, 256, 0, stream>>>(Wk, Wb + 1 * (size_t)Dn * Dn, nw8);
  cvt_bf16_k<<<nw8 / 256, 256, 0, stream>>>(Wv, Wb + 2 * (size_t)Dn * Dn, nw8);
  cvt_bf16_k<<<nw8 / 256, 256, 0, stream>>>(Wo, Wb + 3 * (size_t)Dn * Dn, nw8);

  // Q,K,V = x @ W{q,k,v}^T  -> bf16 (fused over N = 3*2048; 768 blocks)
  gemmY<0, 48, 3><<<768, 256, 0, stream>>>(xb, Wb, (void*)QKV);

  // per-head V transpose
  transpose_v<<<dim3(16, 32), 256, 0, stream>>>(QKV + 2 * (size_t)Mn * Dn, VT);

  // causal attention -> merged [4096, 2048] bf16
  attn_k2<<<dim3(16, 32), 256, 0, stream>>>(QKV, QKV + (size_t)Mn * Dn, VT, Mg);

  // out = merged @ Wo^T -> f32 (256 blocks)
  gemmY<1, 16, 1><<<256, 256, 0, stream>>>(Mg, Wb + 3 * (size_t)Dn * Dn, (void*)out);
}

// Round 7
// 262.462 us; speedup vs baseline: 1.1135x; 1.0156x over previous
//
#include <hip/hip_runtime.h>
#include <hip/hip_bf16.h>

using bf16 = __hip_bfloat16;
typedef __attribute__((ext_vector_type(8))) short bf16x8;   // 8 bf16 = 4 VGPR
typedef __attribute__((ext_vector_type(4))) float f32x4;    // MFMA C/D frag

#define DEVI __device__ __forceinline__

constexpr int Bn = 2, Sn = 2048, Dn = 2048, Hn = 16, DHn = 128;
constexpr int Mn = Bn * Sn;   // 4096

DEVI void gload_lds16(const bf16* g, bf16* l) {
  __builtin_amdgcn_global_load_lds(
      (__attribute__((address_space(1))) void*)g,
      (__attribute__((address_space(3))) void*)l,
      16, 0, 0);
}

// ---------------- f32 -> bf16 convert (vectorized 8/thread) ----------------
__global__ __launch_bounds__(256) void cvt_bf16_k(const float* __restrict__ in,
                                                  bf16* __restrict__ out, int n8) {
  int i = blockIdx.x * 256 + threadIdx.x;
  if (i >= n8) return;
  const float4* p = (const float4*)in + (size_t)i * 2;
  float4 a = p[0], b = p[1];
  union { bf16 h[8]; bf16x8 v; } u;
  u.h[0] = __float2bfloat16(a.x); u.h[1] = __float2bfloat16(a.y);
  u.h[2] = __float2bfloat16(a.z); u.h[3] = __float2bfloat16(a.w);
  u.h[4] = __float2bfloat16(b.x); u.h[5] = __float2bfloat16(b.y);
  u.h[6] = __float2bfloat16(b.z); u.h[7] = __float2bfloat16(b.w);
  *((bf16x8*)out + i) = u.v;
}

// ---------------- GEMM Y: C = A[M,K] * W[N,K]^T ----------------------------
// BM=256, BN=128, BK=32, 256 thr = 4 waves (2M x 2N), per-wave C = 128x64.
// 2-slot LDS ring (48 KB -> 2 blocks/CU), counted vmcnt, phase-spread
// staging, T2 swizzle, T5 setprio. Ledger: tile kt's A0,A2,B0,B1 @ kt-2 ph1;
// A1,A3 @ kt-1 ph0; tile-top vmcnt(4) retires tile kt (last tile vmcnt(0)).
template <int OUTF32, int NTOT, int NMAT>
__global__ __launch_bounds__(256, 2) void gemmY(const bf16* __restrict__ A,
                                                const bf16* __restrict__ W,
                                                void* __restrict__ Cv) {
  constexpr int K = 2048, BK = 32, NT = K / BK;   // 64 K-tiles
  __shared__ bf16 smem[2 * 12288];   // 48 KB: per slot A[256][32] + B[128][32]

  const int nwg = NTOT * 16;
  const int orig = blockIdx.x;
  const int wgid = (orig & 7) * (nwg >> 3) + (orig >> 3);   // XCD swizzle (nwg%8==0)
  const int bm = wgid / NTOT;
  const int bnn = wgid % NTOT;
  constexpr int nper = NTOT / NMAT;
  const int z = bnn / nper;
  const int col0 = (bnn % nper) * 128;

  const int t = threadIdx.x;
  const int wave = t >> 6, lane = t & 63;
  const int wm = wave >> 1, wn = wave & 1;
  const int lr = lane & 15, lg = lane >> 4;
  const int rch = ((lg ^ ((lr >> 1) & 3)) * 8);       // swizzled read chunk
  const int srow = t >> 2;                            // staging row in unit
  const int sch = (t & 3) ^ ((t >> 3) & 3);           // pre-swizzled src chunk

  const bf16* Ab = A + (size_t)(bm * 256 + srow) * K + sch * 8;
  const bf16* Bb = W + (size_t)z * (2048 * 2048) +
                   (size_t)(col0 + srow) * K + sch * 8;

  auto stgA = [&](int slot, int kt, int u) {
    gload_lds16(Ab + (size_t)u * 64 * K + kt * 32,
                smem + slot * 12288 + u * 2048 + t * 8);
  };
  auto stgB = [&](int slot, int kt, int v) {
    gload_lds16(Bb + (size_t)v * 64 * K + kt * 32,
                smem + slot * 12288 + 8192 + v * 2048 + t * 8);
  };

  f32x4 acc[8][4];
  const f32x4 zf = {0.f, 0.f, 0.f, 0.f};
#pragma unroll
  for (int i = 0; i < 8; ++i)
#pragma unroll
    for (int j = 0; j < 4; ++j) acc[i][j] = zf;

  // prologue: tile0 complete (6 units), tile1 partial (A0,A2,B0,B1)
  stgA(0, 0, 0); stgA(0, 0, 1); stgA(0, 0, 2); stgA(0, 0, 3);
  stgB(0, 0, 0); stgB(0, 0, 1);
  stgA(1, 1, 0); stgA(1, 1, 2); stgB(1, 1, 0); stgB(1, 1, 1);

#pragma unroll 2
  for (int kt = 0; kt < NT; ++kt) {
    const int slot = kt & 1;
    const bf16* sAb = smem + slot * 12288;
    const bf16* sBb = sAb + 8192;

    // ---- tile top: guarantee slot kt fully landed, publish to all waves ----
    if (kt == NT - 1) asm volatile("s_waitcnt vmcnt(0)" ::: "memory");
    else              asm volatile("s_waitcnt vmcnt(4)" ::: "memory");
    __builtin_amdgcn_s_barrier();

    // ---- phase 0: af(mh=0) + bv(all); stage kt+1's A1,A3 ----
    bf16x8 af[4], bv[4];
#pragma unroll
    for (int i = 0; i < 4; ++i)
      af[i] = *(const bf16x8*)(sAb + (wm * 128 + i * 16 + lr) * 32 + rch);
#pragma unroll
    for (int n = 0; n < 4; ++n)
      bv[n] = *(const bf16x8*)(sBb + (wn * 64 + n * 16 + lr) * 32 + rch);
    if (kt + 1 < NT) { stgA(slot ^ 1, kt + 1, 1); stgA(slot ^ 1, kt + 1, 3); }
    asm volatile("s_waitcnt lgkmcnt(0)" ::: "memory");
    __builtin_amdgcn_sched_barrier(0);      // rule 18
    __builtin_amdgcn_s_setprio(1);
#pragma unroll
    for (int i = 0; i < 4; ++i)
#pragma unroll
      for (int n = 0; n < 4; ++n)
        acc[i][n] = __builtin_amdgcn_mfma_f32_16x16x32_bf16(af[i], bv[n], acc[i][n], 0, 0, 0);
    __builtin_amdgcn_s_setprio(0);
    __builtin_amdgcn_s_barrier();           // A0,A2,B0,B1 of slot kt now dead

    // ---- phase 1: af(mh=1); stage kt+2's A0,A2,B0,B1 into freed regions ----
#pragma unroll
    for (int i = 0; i < 4; ++i)
      af[i] = *(const bf16x8*)(sAb + (wm * 128 + 64 + i * 16 + lr) * 32 + rch);
    if (kt + 2 < NT) {
      stgA(slot, kt + 2, 0); stgA(slot, kt + 2, 2);
      stgB(slot, kt + 2, 0); stgB(slot, kt + 2, 1);
    }
    asm volatile("s_waitcnt lgkmcnt(0)" ::: "memory");
    __builtin_amdgcn_sched_barrier(0);
    __builtin_amdgcn_s_setprio(1);
#pragma unroll
    for (int i = 0; i < 4; ++i)
#pragma unroll
      for (int n = 0; n < 4; ++n)
        acc[4 + i][n] = __builtin_amdgcn_mfma_f32_16x16x32_bf16(af[i], bv[n], acc[4 + i][n], 0, 0, 0);
    __builtin_amdgcn_s_setprio(0);
    // next tile-top barrier closes this phase.
  }

  // epilogue
  const int r0 = bm * 256 + wm * 128, c0 = col0 + wn * 64;
#pragma unroll
  for (int mm = 0; mm < 8; ++mm)
#pragma unroll
    for (int nn = 0; nn < 4; ++nn) {
      const int rr = r0 + mm * 16 + lg * 4;
      const int cc = c0 + nn * 16 + lr;
#pragma unroll
      for (int r = 0; r < 4; ++r) {
        float v = acc[mm][nn][r];
        if (OUTF32) {
          ((float*)Cv)[(size_t)(rr + r) * 2048 + cc] = v;
        } else {
          bf16* C = (bf16*)Cv + (size_t)z * (Mn * 2048);
          C[(size_t)(rr + r) * 2048 + cc] = __float2bfloat16(v);
        }
      }
    }
}

// ---------------- V transpose: per (b,h)  V[2048,128] -> VT[128,2048] ------
// (head = contiguous 128-row slab of the projection output, plain-view
//  semantics — do NOT treat head as a column group!)
__global__ __launch_bounds__(256, 2) void transpose_v(const bf16* __restrict__ V,
                                                      bf16* __restrict__ VT) {
  __shared__ bf16 tile[128 * 128];   // 32 KB, chunk-XOR-swizzled
  const int kt = blockIdx.x, bh = blockIdx.y;
  const bf16* Vh = V + (size_t)bh * (Sn * DHn);
  bf16* VTh = VT + (size_t)bh * (DHn * Sn);
  const int t = threadIdx.x;
  const int rr = t >> 4, cc = t & 15;
#pragma unroll
  for (int i = 0; i < 8; ++i) {
    int r = rr + i * 16;
    int ch = cc ^ ((r >> 3) & 7);
    *(bf16x8*)(tile + r * 128 + ch * 8) =
        *(const bf16x8*)(Vh + (size_t)(kt * 128 + r) * DHn + cc * 8);
  }
  __syncthreads();
  const int dr = t >> 4, li = t & 15;
#pragma unroll
  for (int i = 0; i < 8; ++i) {
    int dh = dr + i * 16;
    union { bf16 h[8]; bf16x8 v; } u;
#pragma unroll
    for (int j = 0; j < 8; ++j) {
      int k = li * 8 + j;
      int ch = (dh >> 3) ^ ((k >> 3) & 7);
      u.h[j] = tile[k * 128 + ch * 8 + (dh & 7)];
    }
    *(bf16x8*)(VTh + (size_t)dh * Sn + kt * 128 + li * 8) = u.v;
  }
}

// ---------------- causal flash attention v3 --------------------------------
// QBLK=128, 8 waves x 16 q-rows, KBLK=64. Block pairs qb=j with qb=15-j
// (34 tiles each, perfectly balanced; grid 8 x 32 = 256 = 1/CU).
// 2-phase double-buffered K/VT staging via global_load_lds + XOR swizzle.
__global__ __launch_bounds__(512, 1) void attn_k3(const bf16* __restrict__ Q,
                                                  const bf16* __restrict__ K,
                                                  const bf16* __restrict__ VT,
                                                  bf16* __restrict__ Mg) {
  __shared__ bf16 smem[40960];         // 80 KB
  bf16* sK0 = smem;                    // [64][128] swizzled (16 KB)
  bf16* sK1 = smem + 8192;
  bf16* sV0 = smem + 16384;            // [128][64] swizzled (16 KB)
  bf16* sV1 = smem + 24576;
  bf16* sP  = smem + 32768;            // 8 waves x [16][64] swizzled (16 KB)
  bf16* sO  = smem;                    // epilogue reuse [128][128] (32 KB)

  const int j = blockIdx.x;            // pair index 0..7
  const int bh = blockIdx.y;
  const bf16* Qh = Q + (size_t)bh * (Sn * DHn);
  const bf16* Kh = K + (size_t)bh * (Sn * DHn);
  const bf16* VTh = VT + (size_t)bh * (DHn * Sn);
  const int b = bh >> 4, h = bh & 15;

  const int t = threadIdx.x, wave = t >> 6, lane = t & 63;
  const int lr = lane & 15, lg = lane >> 4;

  auto STAGE = [&](int buf, int kt) {
    bf16* dK = buf ? sK1 : sK0;
    bf16* dV = buf ? sV1 : sV0;
#pragma unroll
    for (int i = 0; i < 2; ++i) {
      int c = i * 512 + t;               // 0..1023
      int row = c >> 4, c16 = c & 15;
      gload_lds16(Kh + (size_t)(kt * 64 + row) * DHn + ((c16 ^ (row & 7)) * 8),
                  dK + c * 8);
    }
#pragma unroll
    for (int i = 0; i < 2; ++i) {
      int c = i * 512 + t;
      int row = c >> 3, c8 = c & 7;
      gload_lds16(VTh + (size_t)row * Sn + kt * 64 + ((c8 ^ (row & 7)) * 8),
                  dV + c * 8);
    }
  };

  const f32x4 zf = {0.f, 0.f, 0.f, 0.f};

  for (int pi = 0; pi < 2; ++pi) {
    const int qb = pi ? (15 - j) : j;    // QBLK=128 block index
    const int nt = qb * 2 + 2;
    const int q0 = qb * 128 + wave * 16;

    bf16x8 qf[4];
#pragma unroll
    for (int kk = 0; kk < 4; ++kk)
      qf[kk] = *(const bf16x8*)(Qh + (size_t)(q0 + lr) * DHn + kk * 32 + lg * 8);

    f32x4 o[8];
#pragma unroll
    for (int d = 0; d < 8; ++d) o[d] = zf;
    float mrun[4], lrun[4];
#pragma unroll
    for (int r = 0; r < 4; ++r) { mrun[r] = -3e38f; lrun[r] = 0.f; }

    STAGE(0, 0);
    __syncthreads();   // drains vmcnt(0): buf0 ready
    int cur = 0;

    for (int kt = 0; kt < nt; ++kt) {
      if (kt + 1 < nt) STAGE(cur ^ 1, kt + 1);   // prefetch in flight over compute

      bf16* sKc = cur ? sK1 : sK0;
      bf16* sVc = cur ? sV1 : sV0;

      // S = Q K^T
      f32x4 sfr[4];
#pragma unroll
      for (int nn = 0; nn < 4; ++nn) sfr[nn] = zf;
#pragma unroll
      for (int kk = 0; kk < 4; ++kk)
#pragma unroll
        for (int nn = 0; nn < 4; ++nn) {
          int row = nn * 16 + lr;
          int ch = (kk * 4 + lg) ^ (row & 7);
          bf16x8 kf = *(const bf16x8*)(sKc + row * DHn + ch * 8);
          sfr[nn] = __builtin_amdgcn_mfma_f32_16x16x32_bf16(qf[kk], kf, sfr[nn], 0, 0, 0);
        }

      // online softmax (rows: lg*4+r, cols: nn*16+lr)
      const bool maskt = (kt >= qb * 2);
      float pv[4][4];
#pragma unroll
      for (int nn = 0; nn < 4; ++nn)
#pragma unroll
        for (int r = 0; r < 4; ++r) {
          float v = sfr[nn][r] * (1.0f / 128.0f);
          if (maskt) {
            int kg = kt * 64 + nn * 16 + lr;
            int qg = q0 + lg * 4 + r;
            if (kg > qg) v = -1e30f;
          }
          pv[nn][r] = v;
        }
      float mnew[4], alpha[4], rsum[4];
#pragma unroll
      for (int r = 0; r < 4; ++r) {
        float rm = fmaxf(fmaxf(pv[0][r], pv[1][r]), fmaxf(pv[2][r], pv[3][r]));
        rm = fmaxf(rm, __shfl_xor(rm, 1));
        rm = fmaxf(rm, __shfl_xor(rm, 2));
        rm = fmaxf(rm, __shfl_xor(rm, 4));
        rm = fmaxf(rm, __shfl_xor(rm, 8));
        mnew[r] = fmaxf(mrun[r], rm);
        alpha[r] = __expf(mrun[r] - mnew[r]);
        mrun[r] = mnew[r];
        rsum[r] = 0.f;
      }
#pragma unroll
      for (int nn = 0; nn < 4; ++nn)
#pragma unroll
        for (int r = 0; r < 4; ++r) {
          float p = __expf(pv[nn][r] - mnew[r]);
          pv[nn][r] = p;
          rsum[r] += p;
        }
#pragma unroll
      for (int r = 0; r < 4; ++r) {
        float s = rsum[r];
        s += __shfl_xor(s, 1); s += __shfl_xor(s, 2);
        s += __shfl_xor(s, 4); s += __shfl_xor(s, 8);
        lrun[r] = lrun[r] * alpha[r] + s;
      }
#pragma unroll
      for (int d = 0; d < 8; ++d)
#pragma unroll
        for (int r = 0; r < 4; ++r) o[d][r] *= alpha[r];

      // P -> LDS (swizzled), per-wave [16][64] region
#pragma unroll
      for (int nn = 0; nn < 4; ++nn)
#pragma unroll
        for (int r = 0; r < 4; ++r) {
          int row = lg * 4 + r;
          int chk = (nn * 2 + (lr >> 3)) ^ (row & 7);
          sP[wave * 1024 + row * 64 + chk * 8 + (lr & 7)] = __float2bfloat16(pv[nn][r]);
        }

      // O += P V
      bf16x8 pf[2];
#pragma unroll
      for (int kk = 0; kk < 2; ++kk) {
        int ch = (kk * 4 + lg) ^ (lr & 7);
        pf[kk] = *(const bf16x8*)(sP + wave * 1024 + lr * 64 + ch * 8);
      }
#pragma unroll
      for (int d = 0; d < 8; ++d)
#pragma unroll
        for (int kk = 0; kk < 2; ++kk) {
          int vrow = d * 16 + lr;
          int vch = (kk * 4 + lg) ^ (vrow & 7);
          bf16x8 vf = *(const bf16x8*)(sVc + vrow * 64 + vch * 8);
          o[d] = __builtin_amdgcn_mfma_f32_16x16x32_bf16(pf[kk], vf, o[d], 0, 0, 0);
        }

      __syncthreads();   // drains prefetch vmcnt + all ds reads of cur
      cur ^= 1;
    }

    // epilogue: normalize, stage to LDS (swizzled), coalesced global write
    float inv[4];
#pragma unroll
    for (int r = 0; r < 4; ++r) inv[r] = 1.0f / lrun[r];
#pragma unroll
    for (int d = 0; d < 8; ++d)
#pragma unroll
      for (int r = 0; r < 4; ++r) {
        int row = wave * 16 + lg * 4 + r;
        int col = d * 16 + lr;
        int chk = ((col >> 3) ^ (row & 7));
        sO[row * 128 + chk * 8 + (col & 7)] = __float2bfloat16(o[d][r] * inv[r]);
      }
    __syncthreads();
    bf16* Mh = Mg + ((size_t)(b * Sn + qb * 128)) * Dn + h * DHn;
#pragma unroll
    for (int i = 0; i < 4; ++i) {
      int row = (t >> 4) + i * 32;
      int c16 = t & 15;
      *(bf16x8*)(Mh + (size_t)row * Dn + c16 * 8) =
          *(const bf16x8*)(sO + row * 128 + ((c16 ^ (row & 7)) * 8));
    }
    __syncthreads();   // sO region is re-staged by next pass
  }
}

// ---------------------------------------------------------------------------
extern "C" void kernel_launch(void* const* d_in, const int* in_sizes, int n_in,
                              void* d_out, int out_size, void* d_ws, size_t ws_size,
                              hipStream_t stream) {
  const float* x = (const float*)d_in[0];
  const float* Wq = (const float*)d_in[1];
  const float* Wk = (const float*)d_in[2];
  const float* Wv = (const float*)d_in[3];
  const float* Wo = (const float*)d_in[4];
  float* out = (float*)d_out;

  char* ws = (char*)d_ws;
  bf16* xb = (bf16*)ws;            ws += (size_t)Mn * Dn * 2;        // 16 MB
  bf16* Wb = (bf16*)ws;            ws += (size_t)4 * Dn * Dn * 2;    // 32 MB (q,k,v,o)
  bf16* QKV = (bf16*)ws;           ws += (size_t)3 * Mn * Dn * 2;    // 48 MB
  bf16* VT = (bf16*)ws;            ws += (size_t)Bn * Hn * DHn * Sn * 2; // 16 MB
  bf16* Mg = (bf16*)ws;            ws += (size_t)Mn * Dn * 2;        // 16 MB

  const int nx8 = Mn * Dn / 8;     // 1048576
  const int nw8 = Dn * Dn / 8;     // 524288
  cvt_bf16_k<<<nx8 / 256, 256, 0, stream>>>(x, xb, nx8);
  cvt_bf16_k<<<nw8 / 256, 256, 0, stream>>>(Wq, Wb + 0 * (size_t)Dn * Dn, nw8);
  cvt_bf16_k<<<nw8 / 256, 256, 0, stream>>>(Wk, Wb + 1 * (size_t)Dn * Dn, nw8);
  cvt_bf16_k<<<nw8 / 256, 256, 0, stream>>>(Wv, Wb + 2 * (size_t)Dn * Dn, nw8);
  cvt_bf16_k<<<nw8 / 256, 256, 0, stream>>>(Wo, Wb + 3 * (size_t)Dn * Dn, nw8);

  // Q,K,V = x @ W{q,k,v}^T -> bf16 (768 blocks)
  gemmY<0, 48, 3><<<768, 256, 0, stream>>>(xb, Wb, (void*)QKV);

  // per-head V transpose (plain-view head slabs)
  transpose_v<<<dim3(16, 32), 256, 0, stream>>>(QKV + 2 * (size_t)Mn * Dn, VT);

  // causal attention -> merged [4096, 2048] bf16
  attn_k3<<<dim3(8, 32), 512, 0, stream>>>(QKV, QKV + (size_t)Mn * Dn, VT, Mg);

  // out = merged @ Wo^T -> f32 (256 blocks)
  gemmY<1, 16, 1><<<256, 256, 0, stream>>>(Mg, Wb + 3 * (size_t)Dn * Dn, (void*)out);
}